// Round 10
// baseline (416.905 us; speedup 1.0000x reference)
//
#include <hip/hip_runtime.h>
#include <hip/hip_bf16.h>

typedef short bf16x8 __attribute__((ext_vector_type(8)));
typedef float f32x4 __attribute__((ext_vector_type(4)));
typedef unsigned int u32x4 __attribute__((ext_vector_type(4)));

#define MFMA(a, b, c) __builtin_amdgcn_mfma_f32_16x16x32_bf16((a), (b), (c), 0, 0, 0)

__device__ __forceinline__ unsigned short f2bf(float f) {
    unsigned u = __builtin_bit_cast(unsigned, f);
    unsigned r = u + 0x7FFFu + ((u >> 16) & 1u);   // RNE
    return (unsigned short)(r >> 16);
}

// pair of f32 -> packed bf16 dword (v_cvt_pk_bf16_f32)
__device__ __forceinline__ unsigned pk_bf16(float lo, float hi) {
    __hip_bfloat162 p = __float22bfloat162_rn(make_float2(lo, hi));
    unsigned r;
    __builtin_memcpy(&r, &p, sizeof(r));
    return r;
}

__device__ __forceinline__ float sigm(float x) {
    float e = __builtin_amdgcn_exp2f(-1.44269504088896f * x);
    return __builtin_amdgcn_rcpf(1.0f + e);
}

// DUPLICATE-COLUMN scheme: one wave per 8 batches -> 2048 independent waves
// (2/SIMD), no barriers, no LDS staging, no mid-chain shuffles.
// Lane l: col n = l&15, q = l>>4, batch m = n&7, hi8 = n>>3.
// Batch m is duplicated into B-columns m AND m+8, so lanes (m,*) and (m+8,*)
// compute identical MFMA outputs. Tiles t = 2G+ph (G=i,f,g,o; ph=unit-half).
// Lane (n,q) does cell math on acc[2G + hi8][r] = gate G, unit 16*hi8+4q+r,
// batch m -- a register SELECT (cndmask), not a shuffle. Coverage over the two
// column copies x q x r = all 32 units, each exactly once.
// h-return: own 4 h pack to 2 dwords; partner half arrives via 2 shfl_xor(8);
// B elems 0-3 = units 4q+(0..3) (ph0), elems 4-7 = units 16+4q+(0..3) (ph1).
// Weights pre-scaled: i,f,o rows by -log2(e); g rows by +2*log2(e). c'=2log2e*c.
// accx[8] (x-projection) loop-carried (software pipeline, R5-validated).
__global__ __launch_bounds__(256, 2) void lstm_mfma8_kernel(
    const float* __restrict__ x,     // [B,512,3]
    const float* __restrict__ W_ih,  // [128,3]
    const float* __restrict__ W_hh,  // [128,32]
    const float* __restrict__ b_ih,  // [128]
    const float* __restrict__ b_hh,  // [128]
    const float* __restrict__ W_fc,  // [32]
    const float* __restrict__ b_fc,  // [1]
    float* __restrict__ out,         // [B]
    int n_groups)                    // B/8
{
    const int lane  = threadIdx.x & 63;
    const int wid   = threadIdx.x >> 6;
    const int group = blockIdx.x * 4 + wid;
    if (group >= n_groups) return;

    const int n   = lane & 15;
    const int q   = lane >> 4;
    const int m   = n & 7;
    const bool hi = ((n >> 3) & 1) != 0;

    const float NL2E  = -1.4426950408889634f;  // -log2(e)
    const float P2L2E =  2.8853900817779268f;  // +2*log2(e)

    // A fragments: tile t = 2G + ph; rows g = 32G + 16ph + n
    bf16x8 A_hh[8], A_x[8];
#pragma unroll
    for (int t = 0; t < 8; ++t) {
        const int G  = t >> 1;
        const int ph = t & 1;
        const int g  = 32 * G + 16 * ph + n;
        const float s = (G == 2) ? P2L2E : NL2E;
        bf16x8 a, ax;
#pragma unroll
        for (int j = 0; j < 8; ++j) {
            const int k = 16 * (j >> 2) + 4 * q + (j & 3);
            a[j] = (short)f2bf(s * W_hh[g * 32 + k]);
            float axv = 0.0f;
            if (q == 0 && j < 4) {
                axv = (j < 3) ? s * W_ih[g * 3 + j] : s * (b_ih[g] + b_hh[g]);
            }
            ax[j] = (short)f2bf(axv);
        }
        A_hh[t] = a;
        A_x[t]  = ax;
    }

    const long bn = (long)group * 8 + m;
    const float4* xv = (const float4*)(x + bn * (512L * 3));  // both column copies load batch m

    float cs[4] = {0.f, 0.f, 0.f, 0.f};   // scaled cell state, own 4 units
    float hr[4] = {0.f, 0.f, 0.f, 0.f};
    bf16x8 Bh = {0, 0, 0, 0, 0, 0, 0, 0};
    const f32x4 z4 = {0.f, 0.f, 0.f, 0.f};

    float4 xa = xv[0], xb = xv[1], xc = xv[2];

    // prologue: x-projection for step 0
    f32x4 accx[8];
    {
        unsigned bx01 = pk_bf16(xa.x, xa.y);
        unsigned bx23 = pk_bf16(xa.z, 1.0f);
        u32x4 bxv = {bx01, bx23, bx01, bx23};
        bf16x8 Bx = __builtin_bit_cast(bf16x8, bxv);
#pragma unroll
        for (int t = 0; t < 8; ++t) accx[t] = MFMA(A_x[t], Bx, z4);
    }

#define STEP(XN0, XN1, XN2)                                                     \
    do {                                                                        \
        /* finish gates(t): recurrent MFMA on top of carried x-projection */    \
        f32x4 acc[8];                                                           \
        _Pragma("unroll")                                                       \
        for (int t = 0; t < 8; ++t) acc[t] = MFMA(A_hh[t], Bh, accx[t]);        \
        /* x-projection for t+1 (independent; fills MFMA latency) */            \
        unsigned bx01 = pk_bf16((XN0), (XN1));                                  \
        unsigned bx23 = pk_bf16((XN2), 1.0f);                                   \
        u32x4 bxv = {bx01, bx23, bx01, bx23};                                   \
        bf16x8 Bx = __builtin_bit_cast(bf16x8, bxv);                            \
        _Pragma("unroll")                                                       \
        for (int t = 0; t < 8; ++t) accx[t] = MFMA(A_x[t], Bx, z4);             \
        /* own-gate values: register select, no cross-lane traffic */           \
        float gv[4][4];                                                         \
        _Pragma("unroll")                                                       \
        for (int G = 0; G < 4; ++G) {                                           \
            _Pragma("unroll")                                                   \
            for (int r = 0; r < 4; ++r) {                                       \
                gv[G][r] = hi ? acc[2 * G + 1][r] : acc[2 * G][r];              \
            }                                                                   \
        }                                                                       \
        /* cell math for own 4 units */                                         \
        _Pragma("unroll")                                                       \
        for (int r = 0; r < 4; ++r) {                                           \
            float ei = __builtin_amdgcn_exp2f(gv[0][r]);                        \
            float ef = __builtin_amdgcn_exp2f(gv[1][r]);                        \
            float eg = __builtin_amdgcn_exp2f(gv[2][r]);                        \
            float eo = __builtin_amdgcn_exp2f(gv[3][r]);                        \
            float a1 = 1.0f + ei, b1 = 1.0f + ef;                               \
            float c1 = 1.0f + eg, d1 = 1.0f + eo;                               \
            float rp = __builtin_amdgcn_rcpf(a1 * b1);                          \
            float rq = __builtin_amdgcn_rcpf(c1 * d1);                          \
            float ig = b1 * rp, fg = a1 * rp;                                   \
            float rg = d1 * rq, og = c1 * rq;                                   \
            float gp = fmaf(-5.7707801635558536f, rg, P2L2E);                   \
            cs[r] = fmaf(fg, cs[r], ig * gp);                                   \
            float ec = __builtin_amdgcn_exp2f(cs[r]);                           \
            float tc = fmaf(-2.0f, __builtin_amdgcn_rcpf(1.0f + ec), 1.0f);     \
            hr[r] = og * tc;                                                    \
        }                                                                       \
        /* pack own h; fetch partner half; assemble B for t+1 */                \
        unsigned p0 = pk_bf16(hr[0], hr[1]);                                    \
        unsigned p1 = pk_bf16(hr[2], hr[3]);                                    \
        unsigned r0 = __shfl_xor(p0, 8, 64);                                    \
        unsigned r1 = __shfl_xor(p1, 8, 64);                                    \
        u32x4 bhv = {hi ? r0 : p0, hi ? r1 : p1,                                \
                     hi ? p0 : r0, hi ? p1 : r1};                               \
        Bh = __builtin_bit_cast(bf16x8, bhv);                                   \
    } while (0)

    for (int w4 = 0; w4 < 128; ++w4) {
        const int nw = (w4 < 127) ? (w4 + 1) : 127;
        float4 na = xv[3 * nw + 0];
        float4 nb = xv[3 * nw + 1];
        float4 nc = xv[3 * nw + 2];

        STEP(xa.w, xb.x, xb.y);
        STEP(xb.z, xb.w, xc.x);
        STEP(xc.y, xc.z, xc.w);
        STEP(na.x, na.y, na.z);

        xa = na; xb = nb; xc = nc;
    }
#undef STEP

    // FC + sigmoid: lane's units are 16*hi + 4q + r
    float part = 0.f;
#pragma unroll
    for (int r = 0; r < 4; ++r) {
        part += W_fc[(hi ? 16 : 0) + 4 * q + r] * hr[r];
    }
    part += __shfl_xor(part, 8, 64);    // partner unit-half, same batch
    part += __shfl_xor(part, 16, 64);   // q groups
    part += __shfl_xor(part, 32, 64);
    if (lane == m) {                    // n==m (hi=0), q==0
        out[bn] = sigm(part + b_fc[0]);
    }
}

extern "C" void kernel_launch(void* const* d_in, const int* in_sizes, int n_in,
                              void* d_out, int out_size, void* d_ws, size_t ws_size,
                              hipStream_t stream) {
    const float* x    = (const float*)d_in[0];
    const float* W_ih = (const float*)d_in[1];
    const float* W_hh = (const float*)d_in[2];
    const float* b_ih = (const float*)d_in[3];
    const float* b_hh = (const float*)d_in[4];
    const float* W_fc = (const float*)d_in[5];
    const float* b_fc = (const float*)d_in[6];
    float* out        = (float*)d_out;

    const int n_groups = out_size / 8;       // 2048 independent waves
    const int n_blocks = (n_groups + 3) / 4; // 4 independent waves per 256-thread block

    hipLaunchKernelGGL(lstm_mfma8_kernel, dim3(n_blocks), dim3(256), 0, stream,
                       x, W_ih, W_hh, b_ih, b_hh, W_fc, b_fc, out, n_groups);
}

// Round 11
// 304.257 us; speedup vs baseline: 1.3702x; 1.3702x over previous
//
#include <hip/hip_runtime.h>
#include <hip/hip_bf16.h>

typedef short bf16x8 __attribute__((ext_vector_type(8)));
typedef float f32x4 __attribute__((ext_vector_type(4)));
typedef unsigned int u32x4 __attribute__((ext_vector_type(4)));

#define MFMA(a, b, c) __builtin_amdgcn_mfma_f32_16x16x32_bf16((a), (b), (c), 0, 0, 0)

__device__ __forceinline__ unsigned short f2bf(float f) {
    unsigned u = __builtin_bit_cast(unsigned, f);
    unsigned r = u + 0x7FFFu + ((u >> 16) & 1u);   // RNE
    return (unsigned short)(r >> 16);
}

// pair of f32 -> packed bf16 dword (v_cvt_pk_bf16_f32)
__device__ __forceinline__ unsigned pk_bf16(float lo, float hi) {
    __hip_bfloat162 p = __float22bfloat162_rn(make_float2(lo, hi));
    unsigned r;
    __builtin_memcpy(&r, &p, sizeof(r));
    return r;
}

__device__ __forceinline__ float sigm(float x) {
    float e = __builtin_amdgcn_exp2f(-1.44269504088896f * x);
    return __builtin_amdgcn_rcpf(1.0f + e);
}

// R5 skeleton (best: 318us): one wave per 16 batches, lane-local recurrence,
// no barriers/LDS, loop-carried accx x-projection pipeline.
// NEW (R11): common-denominator cell math — 6 trans/unit instead of 8.
//   ui=2^zi', uf=2^zf', ug=2^zg' (zg' scaled by +2log2e; zi',zf',zo' by -log2e)
//   c' update (scaled c'=2log2e*c), ONE rcp for i,f,g combined:
//     t1=1+ui, t2=1+ug, t3=1+uf; p12=t1*t2; D=t3*p12
//     N = c'*p12 + (2log2e*(ug-1))*t3 ;  c'_new = N * rcp(D)
//   o & tanh(c) share ONE rcp: R2 = rcp((1+uo)(1+ec)), ec=2^min(c',30)
//     o = (1+ec)*R2 ; tanh(c) = 1 - 2*(1+uo)*R2 ; h = o*tanh(c)
//   rcps additionally PAIRED across the lane's lo/hi unit chains:
//     rcp(D_lo*D_hi): D <= 2^56 hard-bound (|z|<=~10) -> product < 2^112 safe
//     rcp(q_lo*q_hi): q <= 2^44 with the c'-clamp at 30 -> product < 2^89 safe
__global__ __launch_bounds__(256, 1) void lstm_mfma11_kernel(
    const float* __restrict__ x,     // [B,512,3]
    const float* __restrict__ W_ih,  // [128,3]
    const float* __restrict__ W_hh,  // [128,32]
    const float* __restrict__ b_ih,  // [128]
    const float* __restrict__ b_hh,  // [128]
    const float* __restrict__ W_fc,  // [32]
    const float* __restrict__ b_fc,  // [1]
    float* __restrict__ out,         // [B]
    int n_groups)
{
    const int lane  = threadIdx.x & 63;
    const int wid   = threadIdx.x >> 6;
    const int group = blockIdx.x * 4 + wid;
    if (group >= n_groups) return;

    const int n = lane & 15;
    const int q = lane >> 4;

    const float NL2E  = -1.4426950408889634f;  // -log2(e)
    const float P2L2E =  2.8853900817779268f;  // +2*log2(e)

    // tiles: (0,1)=i, (2,3)=f, (4,5)=g, (6,7)=o ; even=units 0..15, odd=16..31
    bf16x8 A_hh[8], A_x[8];
#pragma unroll
    for (int t = 0; t < 8; ++t) {
        const int g = 16 * t + n;
        const float s = (t == 4 || t == 5) ? P2L2E : NL2E;
        bf16x8 a, ax;
#pragma unroll
        for (int j = 0; j < 8; ++j) {
            const int k = 16 * (j >> 2) + 4 * q + (j & 3);
            a[j] = (short)f2bf(s * W_hh[g * 32 + k]);
            float axv = 0.0f;
            if (q == 0 && j < 4) {
                axv = (j < 3) ? s * W_ih[g * 3 + j] : s * (b_ih[g] + b_hh[g]);
            }
            ax[j] = (short)f2bf(axv);
        }
        A_hh[t] = a;
        A_x[t]  = ax;
    }

    const long bn = (long)group * 16 + n;
    const float4* xv = (const float4*)(x + bn * (512L * 3));  // 384 float4/batch

    float cs[8] = {0.f, 0.f, 0.f, 0.f, 0.f, 0.f, 0.f, 0.f};
    float h[8]  = {0.f, 0.f, 0.f, 0.f, 0.f, 0.f, 0.f, 0.f};
    bf16x8 Bh = {0, 0, 0, 0, 0, 0, 0, 0};

    float4 xa = xv[0], xb = xv[1], xc = xv[2];

    // prologue: x-projection for step 0
    f32x4 accx[8];
    {
        unsigned bx01 = pk_bf16(xa.x, xa.y);
        unsigned bx23 = pk_bf16(xa.z, 1.0f);
        u32x4 bxv = {bx01, bx23, bx01, bx23};
        bf16x8 Bx = __builtin_bit_cast(bf16x8, bxv);
#pragma unroll
        for (int tt = 0; tt < 8; ++tt) {
            f32x4 z = {0.f, 0.f, 0.f, 0.f};
            accx[tt] = MFMA(A_x[tt], Bx, z);
        }
    }

#define STEP(XN0, XN1, XN2)                                                     \
    do {                                                                        \
        f32x4 acc[8];                                                           \
        _Pragma("unroll")                                                       \
        for (int tt = 0; tt < 8; ++tt) acc[tt] = MFMA(A_hh[tt], Bh, accx[tt]);  \
        unsigned bx01 = pk_bf16((XN0), (XN1));                                  \
        unsigned bx23 = pk_bf16((XN2), 1.0f);                                   \
        u32x4 bxv = {bx01, bx23, bx01, bx23};                                   \
        bf16x8 Bx = __builtin_bit_cast(bf16x8, bxv);                            \
        _Pragma("unroll")                                                       \
        for (int tt = 0; tt < 8; ++tt) {                                        \
            f32x4 z = {0.f, 0.f, 0.f, 0.f};                                     \
            accx[tt] = MFMA(A_x[tt], Bx, z);                                    \
        }                                                                       \
        _Pragma("unroll")                                                       \
        for (int r = 0; r < 4; ++r) {                                           \
            float ui0 = __builtin_amdgcn_exp2f(acc[0][r]);                      \
            float uf0 = __builtin_amdgcn_exp2f(acc[2][r]);                      \
            float ug0 = __builtin_amdgcn_exp2f(acc[4][r]);                      \
            float uo0 = __builtin_amdgcn_exp2f(acc[6][r]);                      \
            float ui1 = __builtin_amdgcn_exp2f(acc[1][r]);                      \
            float uf1 = __builtin_amdgcn_exp2f(acc[3][r]);                      \
            float ug1 = __builtin_amdgcn_exp2f(acc[5][r]);                      \
            float uo1 = __builtin_amdgcn_exp2f(acc[7][r]);                      \
            float t1_0 = 1.0f + ui0, t2_0 = 1.0f + ug0, t3_0 = 1.0f + uf0;      \
            float t1_1 = 1.0f + ui1, t2_1 = 1.0f + ug1, t3_1 = 1.0f + uf1;      \
            float p0 = t1_0 * t2_0, p1 = t1_1 * t2_1;                           \
            float D0 = t3_0 * p0,   D1 = t3_1 * p1;                             \
            float Rp = __builtin_amdgcn_rcpf(D0 * D1);                          \
            float R0 = D1 * Rp, R1 = D0 * Rp;                                   \
            float gm0 = fmaf(P2L2E, ug0, -P2L2E);                               \
            float gm1 = fmaf(P2L2E, ug1, -P2L2E);                               \
            float N0 = fmaf(cs[r],     p0, gm0 * t3_0);                         \
            float N1 = fmaf(cs[4 + r], p1, gm1 * t3_1);                         \
            float c0 = N0 * R0, c1 = N1 * R1;                                   \
            cs[r] = c0; cs[4 + r] = c1;                                         \
            float ec0 = __builtin_amdgcn_exp2f(fminf(c0, 30.0f));               \
            float ec1 = __builtin_amdgcn_exp2f(fminf(c1, 30.0f));               \
            float t4_0 = 1.0f + uo0, t5_0 = 1.0f + ec0;                         \
            float t4_1 = 1.0f + uo1, t5_1 = 1.0f + ec1;                         \
            float q0 = t4_0 * t5_0, q1 = t4_1 * t5_1;                           \
            float Rq = __builtin_amdgcn_rcpf(q0 * q1);                          \
            float R2_0 = q1 * Rq, R2_1 = q0 * Rq;                               \
            float o0 = t5_0 * R2_0, o1 = t5_1 * R2_1;                           \
            float tc0 = fmaf(-(t4_0 + t4_0), R2_0, 1.0f);                       \
            float tc1 = fmaf(-(t4_1 + t4_1), R2_1, 1.0f);                       \
            h[r]     = o0 * tc0;                                                \
            h[4 + r] = o1 * tc1;                                                \
        }                                                                       \
        u32x4 bhv = {pk_bf16(h[0], h[1]), pk_bf16(h[2], h[3]),                  \
                     pk_bf16(h[4], h[5]), pk_bf16(h[6], h[7])};                 \
        Bh = __builtin_bit_cast(bf16x8, bhv);                                   \
    } while (0)

    for (int w4 = 0; w4 < 128; ++w4) {
        const int nw = (w4 < 127) ? (w4 + 1) : 127;
        float4 na = xv[3 * nw + 0];
        float4 nb = xv[3 * nw + 1];
        float4 nc = xv[3 * nw + 2];

        STEP(xa.w, xb.x, xb.y);
        STEP(xb.z, xb.w, xc.x);
        STEP(xc.y, xc.z, xc.w);
        STEP(na.x, na.y, na.z);

        xa = na; xb = nb; xc = nc;
    }
#undef STEP

    // FC + sigmoid
    float part = 0.f;
#pragma unroll
    for (int r = 0; r < 4; ++r) {
        part += W_fc[4 * q + r] * h[r];
        part += W_fc[16 + 4 * q + r] * h[4 + r];
    }
    part += __shfl_xor(part, 16, 64);
    part += __shfl_xor(part, 32, 64);
    if (q == 0) {
        out[bn] = sigm(part + b_fc[0]);
    }
}

extern "C" void kernel_launch(void* const* d_in, const int* in_sizes, int n_in,
                              void* d_out, int out_size, void* d_ws, size_t ws_size,
                              hipStream_t stream) {
    const float* x    = (const float*)d_in[0];
    const float* W_ih = (const float*)d_in[1];
    const float* W_hh = (const float*)d_in[2];
    const float* b_ih = (const float*)d_in[3];
    const float* b_hh = (const float*)d_in[4];
    const float* W_fc = (const float*)d_in[5];
    const float* b_fc = (const float*)d_in[6];
    float* out        = (float*)d_out;

    const int n_groups = out_size / 16;      // 1024 waves
    const int n_blocks = (n_groups + 3) / 4; // 4 waves (256 threads) per block

    hipLaunchKernelGGL(lstm_mfma11_kernel, dim3(n_blocks), dim3(256), 0, stream,
                       x, W_ih, W_hh, b_ih, b_hh, W_fc, b_fc, out, n_groups);
}